// Round 3
// baseline (2904.144 us; speedup 1.0000x reference)
//
#include <hip/hip_runtime.h>
#include <hip/hip_bf16.h>

typedef __attribute__((ext_vector_type(4))) float f32x4;
typedef __attribute__((ext_vector_type(8))) short bf16x8;
typedef __attribute__((ext_vector_type(4))) short bf16x4;

#define MFMA16(a,b,c) __builtin_amdgcn_mfma_f32_16x16x32_bf16(a,b,c,0,0,0)

constexpr int BATCH = 2, SEQ = 2048, EMB = 4096;
constexpr int NHQ = 32, NHKV = 8, HD = 128, GRP = 4;

static __device__ __forceinline__ short f2bf(float f) {
    union { float f; unsigned u; } v; v.f = f;
    unsigned r = v.u + 0x7fff + ((v.u >> 16) & 1);   // RNE; inputs finite
    return (short)(r >> 16);
}

// C[M][N] = A[M][K] * W[N][K]^T + bias. A: f32 (or bf16 if A_BF16), W: f32, acc fp32.
// MODE 0: plain FP32 row-major out[M][N]  (final output)
// MODE 1: fused RoPE, out = [B][NH][T][D] bf16   (Q and K projections)
// MODE 2: out = Vt[B][NHKV][D][T] bf16 (transposed for attention PV operand)
template<int MODE, bool A_BF16>
__global__ __launch_bounds__(256, 2) void gemm_bt(
    const void* __restrict__ Av, const float* __restrict__ W,
    const float* __restrict__ bias, const float* __restrict__ freqs,
    void* __restrict__ outv, int M, int N, int K, int NH)
{
    __shared__ short As[128][72];   // stride 72 bf16 = 36 dwords -> 2-way (free) banks
    __shared__ short Bs[128][72];

    const int tid = threadIdx.x;
    const int lane = tid & 63, wave = tid >> 6;
    const int ln = lane & 15, quad = lane >> 4;
    const int wm = wave >> 1, wn = wave & 1;
    const int rowbase = blockIdx.y * 128;
    const int colbase = blockIdx.x * 128;

    f32x4 acc[4][4];
#pragma unroll
    for (int i = 0; i < 4; i++)
#pragma unroll
        for (int j = 0; j < 4; j++) acc[i][j] = (f32x4){0.f, 0.f, 0.f, 0.f};

    for (int kk = 0; kk < K; kk += 64) {
        __syncthreads();
#pragma unroll
        for (int it = 0; it < 8; ++it) {
            int idx = tid + it * 256;           // 0..2047: 128 rows x 16 chunks of 4
            int r = idx >> 4, c4 = (idx & 15) * 4;
            if (A_BF16) {
                const short* A = (const short*)Av;
                *(bf16x4*)&As[r][c4] = *(const bf16x4*)(A + (size_t)(rowbase + r) * K + kk + c4);
            } else {
                const float* A = (const float*)Av;
                float4 av = *(const float4*)(A + (size_t)(rowbase + r) * K + kk + c4);
                bf16x4 ap; ap[0]=f2bf(av.x); ap[1]=f2bf(av.y); ap[2]=f2bf(av.z); ap[3]=f2bf(av.w);
                *(bf16x4*)&As[r][c4] = ap;
            }
            float4 wv = *(const float4*)(W + (size_t)(colbase + r) * K + kk + c4);
            bf16x4 wp; wp[0]=f2bf(wv.x); wp[1]=f2bf(wv.y); wp[2]=f2bf(wv.z); wp[3]=f2bf(wv.w);
            *(bf16x4*)&Bs[r][c4] = wp;
        }
        __syncthreads();
#pragma unroll
        for (int kc = 0; kc < 2; ++kc) {
            bf16x8 af[4], bfr[4];
#pragma unroll
            for (int i = 0; i < 4; i++)
                af[i] = *(const bf16x8*)&As[wm * 64 + i * 16 + ln][kc * 32 + quad * 8];
#pragma unroll
            for (int i = 0; i < 4; i++)
                bfr[i] = *(const bf16x8*)&Bs[wn * 64 + i * 16 + ln][kc * 32 + quad * 8];
#pragma unroll
            for (int i = 0; i < 4; i++)
#pragma unroll
                for (int j = 0; j < 4; j++)
                    acc[i][j] = MFMA16(af[i], bfr[j], acc[i][j]);
        }
    }

    // epilogue. C/D layout: col = ln, row = quad*4 + reg  [measured m89/m91]
#pragma unroll
    for (int i = 0; i < 4; i++) {
        const int r0 = rowbase + wm * 64 + i * 16 + quad * 4;
#pragma unroll
        for (int j = 0; j < 4; j++) {
            const int c = colbase + wn * 64 + j * 16 + ln;
            const float bv = bias[c];
            if (MODE == 0) {
                float* out = (float*)outv;
#pragma unroll
                for (int rg = 0; rg < 4; rg++)
                    out[(size_t)(r0 + rg) * N + c] = acc[i][j][rg] + bv;
            } else if (MODE == 1) {
                short* out = (short*)outv;
                const int h = c / HD, d = c % HD;
#pragma unroll
                for (int rg = 0; rg < 4; rg++) {
                    const int r = r0 + rg;
                    const int bb = r / SEQ, t = r % SEQ;
                    const float v = acc[i][j][rg] + bv;
                    const float p = __shfl_xor(v, 1);     // pair column lives in lane^1
                    const int fi = (t * (HD / 2) + (d >> 1)) * 2;
                    const float co = freqs[fi], si = freqs[fi + 1];
                    const float y = (d & 1) ? (v * co + p * si) : (v * co - p * si);
                    out[(((size_t)bb * NH + h) * SEQ + t) * HD + d] = f2bf(y);
                }
            } else { // MODE 2: Vt[b][h][d][t], 4 consecutive t -> one 8B store
                short* out = (short*)outv;
                const int h = c / HD, d = c % HD;
                const int bb = r0 / SEQ, t0 = r0 % SEQ;
                bf16x4 pk;
#pragma unroll
                for (int rg = 0; rg < 4; rg++) pk[rg] = f2bf(acc[i][j][rg] + bv);
                *(bf16x4*)(out + (((size_t)bb * NHKV + h) * HD + d) * SEQ + t0) = pk;
            }
        }
    }
}

// Flash attention, causal. Block = 4 waves = 4 Q-heads of one KV group, 32 q-rows each.
__global__ __launch_bounds__(256, 2) void attn(
    const short* __restrict__ Qr, const short* __restrict__ Kr,
    const short* __restrict__ Vt, short* __restrict__ Y)
{
    __shared__ short Ks[64][136];      // [key][d], pad 136 -> 2-way banks
    __shared__ short Vs[128][72];      // [d][key] (V^T), pad 72
    __shared__ short Ps[4][16][72];    // per-wave P round-trip (C-layout -> A-layout)

    const int tid = threadIdx.x;
    const int lane = tid & 63, wave = tid >> 6;
    const int ln = lane & 15, quad = lane >> 4;
    const int qt = blockIdx.x, kvh = blockIdx.y, b = blockIdx.z;
    const int h = kvh * GRP + wave;
    const int qbase = qt * 32;

    const short* Qh = Qr + (((size_t)b * NHQ + h) * SEQ + qbase) * HD;
    const short* Kh = Kr + ((size_t)b * NHKV + kvh) * SEQ * HD;
    const short* Vh = Vt + ((size_t)b * NHKV + kvh) * (size_t)HD * SEQ;

    bf16x8 aQ[2][4];   // A-layout: A[m=ln][k=quad*8+j], dc = 32-wide K chunk
#pragma unroll
    for (int mi = 0; mi < 2; mi++)
#pragma unroll
        for (int dc = 0; dc < 4; dc++)
            aQ[mi][dc] = *(const bf16x8*)(Qh + (size_t)(mi * 16 + ln) * HD + dc * 32 + quad * 8);

    f32x4 oa[2][8];
#pragma unroll
    for (int mi = 0; mi < 2; mi++)
#pragma unroll
        for (int dt = 0; dt < 8; dt++) oa[mi][dt] = (f32x4){0.f, 0.f, 0.f, 0.f};
    float mrun[2][4], lrun[2][4];
#pragma unroll
    for (int mi = 0; mi < 2; mi++)
#pragma unroll
        for (int rg = 0; rg < 4; rg++) { mrun[mi][rg] = -INFINITY; lrun[mi][rg] = 0.f; }

    const int nkt = (qbase + 95) >> 6;   // ceil((qbase+32)/64): stop at the diagonal
    for (int kt = 0; kt < nkt; ++kt) {
        __syncthreads();
        // stage K tile 64x128 (16 chunks/row)
#pragma unroll
        for (int it = 0; it < 4; ++it) {
            int idx = tid + it * 256;
            int r = idx >> 4, c = idx & 15;
            *(bf16x8*)&Ks[r][c * 8] = *(const bf16x8*)(Kh + (size_t)(kt * 64 + r) * HD + c * 8);
        }
        // stage V^T tile 128x64 (8 chunks/row)
#pragma unroll
        for (int it = 0; it < 4; ++it) {
            int idx = tid + it * 256;
            int r = idx >> 3, c = idx & 7;
            *(bf16x8*)&Vs[r][c * 8] = *(const bf16x8*)(Vh + (size_t)r * SEQ + kt * 64 + c * 8);
        }
        __syncthreads();

#pragma unroll
        for (int mi = 0; mi < 2; mi++) {
            float s[4][4];
#pragma unroll
            for (int nt = 0; nt < 4; nt++) {
                f32x4 sa = (f32x4){0.f, 0.f, 0.f, 0.f};
#pragma unroll
                for (int dc = 0; dc < 4; dc++) {
                    bf16x8 bK = *(const bf16x8*)&Ks[nt * 16 + ln][dc * 32 + quad * 8];
                    sa = MFMA16(aQ[mi][dc], bK, sa);
                }
                const int kg = kt * 64 + nt * 16 + ln;   // key idx (C col = ln)
#pragma unroll
                for (int rg = 0; rg < 4; rg++) {
                    const int qg = qbase + mi * 16 + quad * 4 + rg;
                    s[nt][rg] = (kg <= qg) ? sa[rg] * 0.08838834764831845f : -INFINITY;
                }
            }
            float al[4];
#pragma unroll
            for (int rg = 0; rg < 4; rg++) {
                float mx = fmaxf(fmaxf(s[0][rg], s[1][rg]), fmaxf(s[2][rg], s[3][rg]));
                mx = fmaxf(mx, __shfl_xor(mx, 1));
                mx = fmaxf(mx, __shfl_xor(mx, 2));
                mx = fmaxf(mx, __shfl_xor(mx, 4));
                mx = fmaxf(mx, __shfl_xor(mx, 8));
                const float mnew = fmaxf(mrun[mi][rg], mx);
                const float a = __expf(mrun[mi][rg] - mnew);
                float rs = 0.f;
#pragma unroll
                for (int nt = 0; nt < 4; nt++) {
                    const float p = __expf(s[nt][rg] - mnew);
                    s[nt][rg] = p; rs += p;
                }
                rs += __shfl_xor(rs, 1); rs += __shfl_xor(rs, 2);
                rs += __shfl_xor(rs, 4); rs += __shfl_xor(rs, 8);
                lrun[mi][rg] = lrun[mi][rg] * a + rs;
                mrun[mi][rg] = mnew;
                al[rg] = a;
            }
#pragma unroll
            for (int dt = 0; dt < 8; dt++)
#pragma unroll
                for (int rg = 0; rg < 4; rg++) oa[mi][dt][rg] *= al[rg];
            // P: C-layout (row=quad*4+rg, col=nt*16+ln) -> LDS -> A-layout reads
#pragma unroll
            for (int nt = 0; nt < 4; nt++)
#pragma unroll
                for (int rg = 0; rg < 4; rg++)
                    Ps[wave][quad * 4 + rg][nt * 16 + ln] = f2bf(s[nt][rg]);
            __syncthreads();   // uniform across block (loop bounds block-uniform)
#pragma unroll
            for (int kc = 0; kc < 2; kc++) {
                bf16x8 aP = *(const bf16x8*)&Ps[wave][ln][kc * 32 + quad * 8];
#pragma unroll
                for (int dt = 0; dt < 8; dt++) {
                    bf16x8 bV = *(const bf16x8*)&Vs[dt * 16 + ln][kc * 32 + quad * 8];
                    oa[mi][dt] = MFMA16(aP, bV, oa[mi][dt]);
                }
            }
        }
    }

    // epilogue: Y[b][t][h*HD + d]
#pragma unroll
    for (int mi = 0; mi < 2; mi++) {
#pragma unroll
        for (int rg = 0; rg < 4; rg++) {
            const float inv = 1.f / lrun[mi][rg];
            const int t = qbase + mi * 16 + quad * 4 + rg;
            const size_t rowoff = ((size_t)b * SEQ + t) * EMB + h * HD;
#pragma unroll
            for (int dt = 0; dt < 8; dt++)
                Y[rowoff + dt * 16 + ln] = f2bf(oa[mi][dt][rg] * inv);
        }
    }
}

extern "C" void kernel_launch(void* const* d_in, const int* in_sizes, int n_in,
                              void* d_out, int out_size, void* d_ws, size_t ws_size,
                              hipStream_t stream) {
    const float* q  = (const float*)d_in[0];
    const float* k  = (const float*)d_in[1];
    const float* v  = (const float*)d_in[2];
    const float* fr = (const float*)d_in[3];
    // d_in[4] = mask (int32): causal tril, hardcoded in attn
    const float* Wq = (const float*)d_in[5];
    const float* bq = (const float*)d_in[6];
    const float* Wk = (const float*)d_in[7];
    const float* bk = (const float*)d_in[8];
    const float* Wv = (const float*)d_in[9];
    const float* bv = (const float*)d_in[10];
    const float* Wo = (const float*)d_in[11];
    const float* bo = (const float*)d_in[12];

    char* ws = (char*)d_ws;
    short* Qr = (short*)(ws);                    // [B][HQ][T][D]  32 MB bf16
    short* Kr = (short*)(ws + 33554432);         // [B][HKV][T][D]  8 MB
    short* Vt = (short*)(ws + 41943040);         // [B][HKV][D][T]  8 MB
    short* Y  = (short*)(ws + 50331648);         // [B][T][E]      32 MB
    float* out = (float*)d_out;                  // reference output dtype = float32

    const int M = BATCH * SEQ;
    dim3 blk(256);
    gemm_bt<1, false><<<dim3(EMB / 128, M / 128), blk, 0, stream>>>(q, Wq, bq, fr, Qr, M, EMB, EMB, NHQ);
    gemm_bt<1, false><<<dim3((NHKV * HD) / 128, M / 128), blk, 0, stream>>>(k, Wk, bk, fr, Kr, M, NHKV * HD, EMB, NHKV);
    gemm_bt<2, false><<<dim3((NHKV * HD) / 128, M / 128), blk, 0, stream>>>(v, Wv, bv, nullptr, Vt, M, NHKV * HD, EMB, NHKV);
    attn<<<dim3(SEQ / 32, NHKV, BATCH), blk, 0, stream>>>(Qr, Kr, Vt, Y);
    gemm_bt<0, true><<<dim3(EMB / 128, M / 128), blk, 0, stream>>>(Y, Wo, bo, nullptr, out, M, EMB, EMB, 0);
}

// Round 4
// 1665.217 us; speedup vs baseline: 1.7440x; 1.7440x over previous
//
#include <hip/hip_runtime.h>
#include <hip/hip_bf16.h>

typedef __attribute__((ext_vector_type(4))) float f32x4;
typedef __attribute__((ext_vector_type(8))) short bf16x8;
typedef __attribute__((ext_vector_type(4))) short bf16x4;

#define MFMA16(a,b,c) __builtin_amdgcn_mfma_f32_16x16x32_bf16(a,b,c,0,0,0)
// async global->LDS DMA, 16B/lane; LDS dest = uniform base + lane*16
#define GLLDS16(g, l) __builtin_amdgcn_global_load_lds( \
    (const __attribute__((address_space(1))) unsigned int*)(g), \
    (__attribute__((address_space(3))) unsigned int*)(l), 16, 0, 0)

constexpr int BATCH = 2, SEQ = 2048, EMB = 4096;
constexpr int NHQ = 32, NHKV = 8, HD = 128, GRP = 4;

static __device__ __forceinline__ short f2bf(float f) {
    union { float f; unsigned u; } v; v.f = f;
    unsigned r = v.u + 0x7fff + ((v.u >> 16) & 1);   // RNE; inputs finite
    return (short)(r >> 16);
}
static __device__ __forceinline__ bf16x8 cvt8(f32x4 a, f32x4 b) {
    bf16x8 r;
    r[0]=f2bf(a[0]); r[1]=f2bf(a[1]); r[2]=f2bf(a[2]); r[3]=f2bf(a[3]);
    r[4]=f2bf(b[0]); r[5]=f2bf(b[1]); r[6]=f2bf(b[2]); r[7]=f2bf(b[3]);
    return r;
}

// f32 -> bf16 bulk convert (memory-bound, ~16us for 64MB in)
__global__ __launch_bounds__(256) void cvt_bf16(
    const float* __restrict__ src, short* __restrict__ dst, int n8)
{
    int i = blockIdx.x * blockDim.x + threadIdx.x;
    const int stride = gridDim.x * blockDim.x;
    for (; i < n8; i += stride) {
        f32x4 a = *(const f32x4*)(src + (size_t)i * 8);
        f32x4 b = *(const f32x4*)(src + (size_t)i * 8 + 4);
        *(bf16x8*)(dst + (size_t)i * 8) = cvt8(a, b);
    }
}

// C[M][N] = A[M][K] * W[N][K]^T + bias. W: bf16 (pre-converted). A: f32 or bf16.
// MODE 0: fp32 row-major out[M][N]  (final output)
// MODE 1: fused RoPE, out = [B][NH][T][D] bf16   (Q and K projections)
// MODE 2: out = Vt[B][NHKV][D][T] bf16 (transposed for attention PV operand)
template<int MODE, bool A_F32>
__global__ __launch_bounds__(256) void gemm_bt(
    const void* __restrict__ Av, const short* __restrict__ W,
    const float* __restrict__ bias, const float* __restrict__ freqs,
    void* __restrict__ outv, int M, int N, int K, int NH)
{
    // unpadded: layouts must match global_load_lds lane order (no padding!)
    constexpr int ABYTES = A_F32 ? (128 * 64 * 4) : (128 * 64 * 2);
    __shared__ char sAraw[ABYTES];
    __shared__ short Bs[128][64];
    float (*Asf)[64] = (float(*)[64])sAraw;
    short (*Asb)[64] = (short(*)[64])sAraw;

    const int tid = threadIdx.x;
    const int lane = tid & 63, wave = tid >> 6;
    const int ln = lane & 15, quad = lane >> 4;
    const int wm = wave >> 1, wn = wave & 1;
    const int rowbase = blockIdx.y * 128;
    const int colbase = blockIdx.x * 128;

    f32x4 acc[4][4];
#pragma unroll
    for (int i = 0; i < 4; i++)
#pragma unroll
        for (int j = 0; j < 4; j++) acc[i][j] = (f32x4){0.f, 0.f, 0.f, 0.f};

    for (int kk = 0; kk < K; kk += 64) {
        __syncthreads();   // barrier drains prior ds_reads before overwrite
        if (A_F32) {
            const float* A = (const float*)Av;
            // f32 tile 128x64: 16 chunks(16B)/row, 4 rows per wave-load, 8 loads/wave
#pragma unroll
            for (int i = 0; i < 8; ++i) {
                const int row = wave * 32 + i * 4;
                const float* g = A + (size_t)(rowbase + row + (lane >> 4)) * K + kk + (lane & 15) * 4;
                GLLDS16(g, &Asf[row][0]);
            }
        } else {
            const short* A = (const short*)Av;
            // bf16 tile 128x64: 8 chunks/row, 8 rows per wave-load, 4 loads/wave
#pragma unroll
            for (int i = 0; i < 4; ++i) {
                const int row = wave * 32 + i * 8;
                const short* g = A + (size_t)(rowbase + row + (lane >> 3)) * K + kk + (lane & 7) * 8;
                GLLDS16(g, &Asb[row][0]);
            }
        }
#pragma unroll
        for (int i = 0; i < 4; ++i) {
            const int row = wave * 32 + i * 8;
            const short* g = W + (size_t)(colbase + row + (lane >> 3)) * K + kk + (lane & 7) * 8;
            GLLDS16(g, &Bs[row][0]);
        }
        __syncthreads();   // drains vmcnt (global_load_lds) per m97 semantics

#pragma unroll
        for (int kc = 0; kc < 2; ++kc) {
            bf16x8 af[4], bfr[4];
#pragma unroll
            for (int i = 0; i < 4; i++) {
                if (A_F32) {
                    f32x4 lo = *(const f32x4*)&Asf[wm * 64 + i * 16 + ln][kc * 32 + quad * 8];
                    f32x4 hi = *(const f32x4*)&Asf[wm * 64 + i * 16 + ln][kc * 32 + quad * 8 + 4];
                    af[i] = cvt8(lo, hi);
                } else {
                    af[i] = *(const bf16x8*)&Asb[wm * 64 + i * 16 + ln][kc * 32 + quad * 8];
                }
            }
#pragma unroll
            for (int i = 0; i < 4; i++)
                bfr[i] = *(const bf16x8*)&Bs[wn * 64 + i * 16 + ln][kc * 32 + quad * 8];
#pragma unroll
            for (int i = 0; i < 4; i++)
#pragma unroll
                for (int j = 0; j < 4; j++)
                    acc[i][j] = MFMA16(af[i], bfr[j], acc[i][j]);
        }
    }

    // epilogue. C/D layout: col = ln, row = quad*4 + reg  [measured m89/m91]
#pragma unroll
    for (int i = 0; i < 4; i++) {
        const int r0 = rowbase + wm * 64 + i * 16 + quad * 4;
#pragma unroll
        for (int j = 0; j < 4; j++) {
            const int c = colbase + wn * 64 + j * 16 + ln;
            const float bv = bias[c];
            if (MODE == 0) {
                float* out = (float*)outv;
#pragma unroll
                for (int rg = 0; rg < 4; rg++)
                    out[(size_t)(r0 + rg) * N + c] = acc[i][j][rg] + bv;
            } else if (MODE == 1) {
                short* out = (short*)outv;
                const int h = c / HD, d = c % HD;
#pragma unroll
                for (int rg = 0; rg < 4; rg++) {
                    const int r = r0 + rg;
                    const int bb = r / SEQ, t = r % SEQ;
                    const float v = acc[i][j][rg] + bv;
                    const float p = __shfl_xor(v, 1);     // pair column lives in lane^1
                    const int fi = (t * (HD / 2) + (d >> 1)) * 2;
                    const float co = freqs[fi], si = freqs[fi + 1];
                    const float y = (d & 1) ? (v * co + p * si) : (v * co - p * si);
                    out[(((size_t)bb * NH + h) * SEQ + t) * HD + d] = f2bf(y);
                }
            } else { // MODE 2: Vt[b][h][d][t], 4 consecutive t -> one 8B store
                short* out = (short*)outv;
                const int h = c / HD, d = c % HD;
                const int bb = r0 / SEQ, t0 = r0 % SEQ;
                bf16x4 pk;
#pragma unroll
                for (int rg = 0; rg < 4; rg++) pk[rg] = f2bf(acc[i][j][rg] + bv);
                *(bf16x4*)(out + (((size_t)bb * NHKV + h) * HD + d) * SEQ + t0) = pk;
            }
        }
    }
}

// Flash attention, causal. Block = 4 waves = 4 Q-heads of one KV group, 32 q-rows each.
__global__ __launch_bounds__(256) void attn(
    const short* __restrict__ Qr, const short* __restrict__ Kr,
    const short* __restrict__ Vt, short* __restrict__ Y)
{
    __shared__ short Ks[64][128];      // [key][d]   unpadded (global_load_lds)
    __shared__ short Vs[128][64];      // [d][key]   unpadded (global_load_lds)
    __shared__ short Ps[4][16][72];    // per-wave P round-trip (padded ok: lane stores)

    const int tid = threadIdx.x;
    const int lane = tid & 63, wave = tid >> 6;
    const int ln = lane & 15, quad = lane >> 4;
    const int qt = blockIdx.x, kvh = blockIdx.y, b = blockIdx.z;
    const int h = kvh * GRP + wave;
    const int qbase = qt * 32;

    const short* Qh = Qr + (((size_t)b * NHQ + h) * SEQ + qbase) * HD;
    const short* Kh = Kr + ((size_t)b * NHKV + kvh) * SEQ * HD;
    const short* Vh = Vt + ((size_t)b * NHKV + kvh) * (size_t)HD * SEQ;

    bf16x8 aQ[2][4];   // A-layout: A[m=ln][k=quad*8+j], dc = 32-wide K chunk
#pragma unroll
    for (int mi = 0; mi < 2; mi++)
#pragma unroll
        for (int dc = 0; dc < 4; dc++)
            aQ[mi][dc] = *(const bf16x8*)(Qh + (size_t)(mi * 16 + ln) * HD + dc * 32 + quad * 8);

    f32x4 oa[2][8];
#pragma unroll
    for (int mi = 0; mi < 2; mi++)
#pragma unroll
        for (int dt = 0; dt < 8; dt++) oa[mi][dt] = (f32x4){0.f, 0.f, 0.f, 0.f};
    float mrun[2][4], lrun[2][4];
#pragma unroll
    for (int mi = 0; mi < 2; mi++)
#pragma unroll
        for (int rg = 0; rg < 4; rg++) { mrun[mi][rg] = -INFINITY; lrun[mi][rg] = 0.f; }

    const int nkt = (qbase + 95) >> 6;   // ceil((qbase+32)/64): stop at the diagonal
    for (int kt = 0; kt < nkt; ++kt) {
        __syncthreads();
        // K tile 64x128: 16 chunks/row, 4 rows per wave-load, 4 loads/wave
#pragma unroll
        for (int i = 0; i < 4; ++i) {
            const int row = wave * 16 + i * 4;
            const short* g = Kh + (size_t)(kt * 64 + row + (lane >> 4)) * HD + (lane & 15) * 8;
            GLLDS16(g, &Ks[row][0]);
        }
        // V^T tile 128x64: 8 chunks/row, 8 rows per wave-load, 4 loads/wave
#pragma unroll
        for (int i = 0; i < 4; ++i) {
            const int row = wave * 32 + i * 8;
            const short* g = Vh + (size_t)(row + (lane >> 3)) * SEQ + kt * 64 + (lane & 7) * 8;
            GLLDS16(g, &Vs[row][0]);
        }
        __syncthreads();

#pragma unroll
        for (int mi = 0; mi < 2; mi++) {
            float s[4][4];
#pragma unroll
            for (int nt = 0; nt < 4; nt++) {
                f32x4 sa = (f32x4){0.f, 0.f, 0.f, 0.f};
#pragma unroll
                for (int dc = 0; dc < 4; dc++) {
                    bf16x8 bK = *(const bf16x8*)&Ks[nt * 16 + ln][dc * 32 + quad * 8];
                    sa = MFMA16(aQ[mi][dc], bK, sa);
                }
                const int kg = kt * 64 + nt * 16 + ln;   // key idx (C col = ln)
#pragma unroll
                for (int rg = 0; rg < 4; rg++) {
                    const int qg = qbase + mi * 16 + quad * 4 + rg;
                    s[nt][rg] = (kg <= qg) ? sa[rg] * 0.08838834764831845f : -INFINITY;
                }
            }
            float al[4];
#pragma unroll
            for (int rg = 0; rg < 4; rg++) {
                float mx = fmaxf(fmaxf(s[0][rg], s[1][rg]), fmaxf(s[2][rg], s[3][rg]));
                mx = fmaxf(mx, __shfl_xor(mx, 1));
                mx = fmaxf(mx, __shfl_xor(mx, 2));
                mx = fmaxf(mx, __shfl_xor(mx, 4));
                mx = fmaxf(mx, __shfl_xor(mx, 8));
                const float mnew = fmaxf(mrun[mi][rg], mx);
                const float a = __expf(mrun[mi][rg] - mnew);
                float rs = 0.f;
#pragma unroll
                for (int nt = 0; nt < 4; nt++) {
                    const float p = __expf(s[nt][rg] - mnew);
                    s[nt][rg] = p; rs += p;
                }
                rs += __shfl_xor(rs, 1); rs += __shfl_xor(rs, 2);
                rs += __shfl_xor(rs, 4); rs += __shfl_xor(rs, 8);
                lrun[mi][rg] = lrun[mi][rg] * a + rs;
                mrun[mi][rg] = mnew;
                al[rg] = a;
            }
#pragma unroll
            for (int dt = 0; dt < 8; dt++)
#pragma unroll
                for (int rg = 0; rg < 4; rg++) oa[mi][dt][rg] *= al[rg];
            // P: C-layout (row=quad*4+rg, col=nt*16+ln) -> LDS -> A-layout reads
#pragma unroll
            for (int nt = 0; nt < 4; nt++)
#pragma unroll
                for (int rg = 0; rg < 4; rg++)
                    Ps[wave][quad * 4 + rg][nt * 16 + ln] = f2bf(s[nt][rg]);
            __syncthreads();   // uniform across block (loop bounds block-uniform)
#pragma unroll
            for (int kc = 0; kc < 2; kc++) {
                bf16x8 aP = *(const bf16x8*)&Ps[wave][ln][kc * 32 + quad * 8];
#pragma unroll
                for (int dt = 0; dt < 8; dt++) {
                    bf16x8 bV = *(const bf16x8*)&Vs[dt * 16 + ln][kc * 32 + quad * 8];
                    oa[mi][dt] = MFMA16(aP, bV, oa[mi][dt]);
                }
            }
        }
    }

    // epilogue: Y[b][t][h*HD + d]
#pragma unroll
    for (int mi = 0; mi < 2; mi++) {
#pragma unroll
        for (int rg = 0; rg < 4; rg++) {
            const float inv = 1.f / lrun[mi][rg];
            const int t = qbase + mi * 16 + quad * 4 + rg;
            const size_t rowoff = ((size_t)b * SEQ + t) * EMB + h * HD;
#pragma unroll
            for (int dt = 0; dt < 8; dt++)
                Y[rowoff + dt * 16 + ln] = f2bf(oa[mi][dt][rg] * inv);
        }
    }
}

extern "C" void kernel_launch(void* const* d_in, const int* in_sizes, int n_in,
                              void* d_out, int out_size, void* d_ws, size_t ws_size,
                              hipStream_t stream) {
    const float* q  = (const float*)d_in[0];
    const float* k  = (const float*)d_in[1];
    const float* v  = (const float*)d_in[2];
    const float* fr = (const float*)d_in[3];
    // d_in[4] = mask (int32): causal tril, hardcoded in attn
    const float* Wq = (const float*)d_in[5];
    const float* bq = (const float*)d_in[6];
    const float* Wk = (const float*)d_in[7];
    const float* bk = (const float*)d_in[8];
    const float* Wv = (const float*)d_in[9];
    const float* bv = (const float*)d_in[10];
    const float* Wo = (const float*)d_in[11];
    const float* bo = (const float*)d_in[12];

    char* ws = (char*)d_ws;
    short* Qr = (short*)(ws);                    // [B][HQ][T][D]   32 MiB bf16
    short* Kr = (short*)(ws + 33554432);         // [B][HKV][T][D]   8 MiB
    short* Vt = (short*)(ws + 41943040);         // [B][HKV][D][T]   8 MiB
    short* Y  = (short*)(ws + 50331648);         // [B][T][E]       32 MiB
    short* Wb = (short*)(ws + 83886080);         // bf16 weight buf 32 MiB (reused 4x)
    float* out = (float*)d_out;                  // reference output dtype = float32

    const int M = BATCH * SEQ;
    dim3 blk(256);
    const int big8 = EMB * EMB / 8, small8 = NHKV * HD * EMB / 8;

    cvt_bf16<<<1024, blk, 0, stream>>>(Wq, Wb, big8);
    gemm_bt<1, true><<<dim3(EMB / 128, M / 128), blk, 0, stream>>>(q, Wb, bq, fr, Qr, M, EMB, EMB, NHQ);
    cvt_bf16<<<1024, blk, 0, stream>>>(Wk, Wb, small8);
    gemm_bt<1, true><<<dim3((NHKV * HD) / 128, M / 128), blk, 0, stream>>>(k, Wb, bk, fr, Kr, M, NHKV * HD, EMB, NHKV);
    cvt_bf16<<<1024, blk, 0, stream>>>(Wv, Wb, small8);
    gemm_bt<2, true><<<dim3((NHKV * HD) / 128, M / 128), blk, 0, stream>>>(v, Wb, bv, nullptr, Vt, M, NHKV * HD, EMB, NHKV);
    attn<<<dim3(SEQ / 32, NHKV, BATCH), blk, 0, stream>>>(Qr, Kr, Vt, Y);
    cvt_bf16<<<1024, blk, 0, stream>>>(Wo, Wb, big8);
    gemm_bt<0, false><<<dim3(EMB / 128, M / 128), blk, 0, stream>>>(Y, Wb, bo, nullptr, out, M, EMB, EMB, 0);
}